// Round 10
// baseline (139.729 us; speedup 1.0000x reference)
//
#include <hip/hip_runtime.h>

// Problem: CausalSelfAttention  B=2 T=2048 C=1024 H=16 D=64, fp32 in/out.
// Pipeline: cvt(x) -> tconv(Wqkv,Wout) -> GEMM1(256^2 K-split 4-phase pipelined)
//           -> rope_pack -> vtrans -> attn7 -> GEMM2(128^2, fp32 out).

#define B_  2
#define T_  2048
#define C_  1024
#define H_  16
#define D_  64
#define N3_ 3072

typedef unsigned short ushortx8 __attribute__((ext_vector_type(8)));
typedef unsigned short ushortx4 __attribute__((ext_vector_type(4)));
typedef short bf16x8 __attribute__((ext_vector_type(8)));
typedef float f32x4 __attribute__((ext_vector_type(4)));
typedef float f32x16 __attribute__((ext_vector_type(16)));
typedef unsigned int uintx2 __attribute__((ext_vector_type(2)));

__device__ __forceinline__ unsigned short f2bf(float f) {
  union { float f; unsigned u; } v; v.f = f;
  unsigned r = v.u + 0x7FFFu + ((v.u >> 16) & 1u);   // RNE
  return (unsigned short)(r >> 16);
}
__device__ __forceinline__ float bf2f(unsigned short h) {
  union { unsigned u; float f; } v; v.u = ((unsigned)h) << 16;
  return v.f;
}
// pack two f32 -> 2xbf16 in one u32 (no builtin exists; m240)
__device__ __forceinline__ unsigned cvtpk_bf16(float lo, float hi) {
  unsigned r; asm("v_cvt_pk_bf16_f32 %0, %1, %2" : "=v"(r) : "v"(lo), "v"(hi));
  return r;
}
// async global->LDS, 16B per lane; dst must be wave-uniform (HW adds lane*16)
__device__ __forceinline__ void gload_lds16(const void* g, void* l) {
  __builtin_amdgcn_global_load_lds((const __attribute__((address_space(1))) void*)g,
                                   (__attribute__((address_space(3))) void*)l,
                                   16, 0, 0);
}

// ---------------- fp32 -> bf16 convert (x) ----------------
__global__ __launch_bounds__(256) void cvt_x_kernel(const float* __restrict__ x,
                                                    unsigned short* __restrict__ xb) {
  size_t i = ((size_t)blockIdx.x * 256 + threadIdx.x) * 4;
  const float4 v = *(const float4*)(x + i);
  ushortx4 o;
  o[0] = f2bf(v.x); o[1] = f2bf(v.y); o[2] = f2bf(v.z); o[3] = f2bf(v.w);
  *(ushortx4*)(xb + i) = o;
}

// ------------- transpose+convert: W[K][N] f32 -> WT[N][K] bf16 -------------
__global__ __launch_bounds__(256) void tconv_kernel(const float* __restrict__ W,
                                                    unsigned short* __restrict__ WT,
                                                    int K, int N) {
  __shared__ float tile[32][33];
  const int n0 = blockIdx.x * 32, k0 = blockIdx.y * 32;
  const int tx = threadIdx.x & 31, ty = threadIdx.x >> 5;
#pragma unroll
  for (int i = 0; i < 4; ++i)
    tile[ty + i * 8][tx] = W[(size_t)(k0 + ty + i * 8) * N + n0 + tx];
  __syncthreads();
#pragma unroll
  for (int i = 0; i < 4; ++i)
    WT[(size_t)(n0 + ty + i * 8) * K + k0 + tx] = f2bf(tile[tx][ty + i * 8]);
}

// ---- GEMM-256 v2: C = A * BT^T, 256x256 tile, 8 waves (2Mx4N), BK=64.
//      K-SPLIT half-tiles [dbuf][kch][256x32]: every wave consumes kc0 in
//      phases 0-1, kc1 in phases 2-3 -> staggered counted vmcnt(6) (T4).
//      Per phase: {stage 1 half-tile of kt+1 ; [vmcnt] ; barrier ; ds_read ;
//      setprio(1) 16 MFMA setprio(0) ; barrier}  (T2 swizzle, T3/T5).
__global__ __launch_bounds__(512, 1) void gemm256_kernel(const unsigned short* __restrict__ A,
                                                         const unsigned short* __restrict__ BT,
                                                         unsigned short* __restrict__ Cb,
                                                         int M, int N, int K) {
  __shared__ unsigned short Akl[2][2][256 * 32];   // [dbuf][kch] 16KB each
  __shared__ unsigned short Bkl[2][2][256 * 32];   // -> 128KB total
  const int tid = threadIdx.x, w = tid >> 6, l = tid & 63;
  const int wm = w >> 2, wn = w & 3;               // 2M x 4N wave grid
  const int lg = l >> 4, lr = l & 15;
  const int ric = l >> 2, sl = l & 3;              // staging: row-in-chunk, dest seg
  // bijective XCD swizzle: nwg=192, 192%8==0, chunk=24
  const int bid = blockIdx.x;
  const int swzb = (bid & 7) * 24 + (bid >> 3);
  const int nbn = N >> 8;
  const int bm = swzb / nbn, bn = swzb % nbn;
  const int m0 = bm * 256, n0 = bn * 256;
  const int NT = K >> 6;

  f32x4 acc[8][4];
#pragma unroll
  for (int i = 0; i < 8; ++i)
#pragma unroll
    for (int j = 0; j < 4; ++j) acc[i][j] = f32x4{0.f, 0.f, 0.f, 0.f};

  // stage one (side, kch) half-tile (256 rows x 32 cols) of K-tile at k0 into dbuf d.
  // chunk ch = w + 8*j covers rows ch*16..+15; lane: row ric, dest seg sl;
  // source seg pre-swizzled cs = sl ^ (row & 3)  (involution, matches read).
  auto stageH = [&](int d, int side, int kch, int k0) {
#pragma unroll
    for (int j = 0; j < 2; ++j) {
      const int ch = w + 8 * j;
      const int r = ch * 16 + ric;
      const int cs = sl ^ (r & 3);
      if (side == 0)
        gload_lds16(A + (size_t)(m0 + r) * K + k0 + kch * 32 + cs * 8, &Akl[d][kch][ch * 512]);
      else
        gload_lds16(BT + (size_t)(n0 + r) * K + k0 + kch * 32 + cs * 8, &Bkl[d][kch][ch * 512]);
    }
  };

  // prologue: tile 0, issue order A-k0, B-k0, A-k1, B-k1 (8 loads/thread)
  stageH(0, 0, 0, 0); stageH(0, 1, 0, 0); stageH(0, 0, 1, 0); stageH(0, 1, 1, 0);

  for (int kt = 0; kt < NT; ++kt) {
    const int d = kt & 1, nd = d ^ 1;
    const int k1 = (kt + 1) * 64;
    const bool more = (kt + 1 < NT);
    bf16x8 bfr[4];
#pragma unroll
    for (int ph = 0; ph < 4; ++ph) {
      const int kc = ph >> 1;        // k-slice: 0,0,1,1
      const int mh = ph & 1;         // mi half: 0 -> mi 0..3, 1 -> mi 4..7
      // stage for kt+1: ph0=A-k0, ph1=B-k0, ph2=A-k1, ph3=B-k1
      if (more) stageH(nd, ph & 1, ph >> 1, k1);
      // staggered data-ready sync (own loads) then block-wide barrier
      if (ph == 0) {
        if (more) asm volatile("s_waitcnt vmcnt(6)" ::: "memory");
        else      asm volatile("s_waitcnt vmcnt(4)" ::: "memory");
      } else if (ph == 2) {
        if (more) asm volatile("s_waitcnt vmcnt(6)" ::: "memory");
        else      asm volatile("s_waitcnt vmcnt(0)" ::: "memory");
      }
      __builtin_amdgcn_s_barrier();
      asm volatile("" ::: "memory");   // compiler fence: no LDS reads hoist above
      if (mh == 0) {                   // new k-slice: load B-frags (kept for ph+1)
#pragma unroll
        for (int nj = 0; nj < 4; ++nj) {
          const int r = wn * 64 + nj * 16 + lr;
          bfr[nj] = *(const bf16x8*)(&Bkl[d][kc][r * 32 + (lg ^ (r & 3)) * 8]);
        }
      }
      bf16x8 af[4];
#pragma unroll
      for (int i = 0; i < 4; ++i) {
        const int r = wm * 128 + (mh * 4 + i) * 16 + lr;
        af[i] = *(const bf16x8*)(&Akl[d][kc][r * 32 + (lg ^ (r & 3)) * 8]);
      }
      __builtin_amdgcn_s_setprio(1);
#pragma unroll
      for (int i = 0; i < 4; ++i)
#pragma unroll
        for (int nj = 0; nj < 4; ++nj)
          acc[mh * 4 + i][nj] = __builtin_amdgcn_mfma_f32_16x16x32_bf16(
              af[i], bfr[nj], acc[mh * 4 + i][nj], 0, 0, 0);
      __builtin_amdgcn_s_setprio(0);
      asm volatile("" ::: "memory");   // reads of buf d retired (lgkm before MFMA)
      __builtin_amdgcn_s_barrier();    // close phase; enables kt+1 overwrite of d
    }
  }
  // epilogue: C/D row=(lane>>4)*4+j (m-side), col=lane&15 (n-side)
#pragma unroll
  for (int mi = 0; mi < 8; ++mi)
#pragma unroll
    for (int nj = 0; nj < 4; ++nj)
#pragma unroll
      for (int j = 0; j < 4; ++j) {
        const int row = m0 + wm * 128 + mi * 16 + lg * 4 + j;
        const int col = n0 + wn * 64 + nj * 16 + lr;
        Cb[(size_t)row * N + col] = f2bf(acc[mi][nj][j]);
      }
}

// ---------------- GEMM: C[M][N] = A[M][K] * BT[N][K]^T (bf16 MFMA) ----------------
// 128x128 tile, BK=64, 4 waves (each 64x64), global_load_lds w/ XOR-swizzled source.
template <int OUTF32>
__global__ __launch_bounds__(256) void gemm_bt_kernel(const unsigned short* __restrict__ A,
                                                      const unsigned short* __restrict__ BT,
                                                      void* __restrict__ Cptr,
                                                      int M, int N, int K) {
  __shared__ unsigned short Alds[128 * 64];
  __shared__ unsigned short Blds[128 * 64];
  const int tid = threadIdx.x;
  const int w = tid >> 6, l = tid & 63;
  const int wr = w >> 1, wc = w & 1;
  const int lg = l >> 4, lr = l & 15;
  const int m0 = blockIdx.y * 128, n0 = blockIdx.x * 128;
  const int lr8 = l >> 3;                 // row within 8-row chunk
  const int lc8 = (l & 7) ^ lr8;          // pre-swizzled source col16 (T2 st-style)

  f32x4 acc[4][4];
#pragma unroll
  for (int i = 0; i < 4; ++i)
#pragma unroll
    for (int j = 0; j < 4; ++j) acc[i][j] = f32x4{0.f, 0.f, 0.f, 0.f};

  for (int k0 = 0; k0 < K; k0 += 64) {
    __syncthreads();
#pragma unroll
    for (int i = 0; i < 4; ++i) {
      const int ch = w * 4 + i;           // 16 chunks of 1024B per tile
      gload_lds16(A + (size_t)(m0 + ch * 8 + lr8) * K + k0 + lc8 * 8, &Alds[ch * 512]);
      gload_lds16(BT + (size_t)(n0 + ch * 8 + lr8) * K + k0 + lc8 * 8, &Blds[ch * 512]);
    }
    __syncthreads();
#pragma unroll
    for (int kc = 0; kc < 2; ++kc) {
      bf16x8 af[4], bfr[4];
#pragma unroll
      for (int mi = 0; mi < 4; ++mi) {
        const int row = wr * 64 + mi * 16 + lr;
        const int c16 = (kc * 4 + lg) ^ (row & 7);
        af[mi] = *(const bf16x8*)(&Alds[row * 64 + c16 * 8]);
      }
#pragma unroll
      for (int nj = 0; nj < 4; ++nj) {
        const int row = wc * 64 + nj * 16 + lr;
        const int c16 = (kc * 4 + lg) ^ (row & 7);
        bfr[nj] = *(const bf16x8*)(&Blds[row * 64 + c16 * 8]);
      }
#pragma unroll
      for (int mi = 0; mi < 4; ++mi)
#pragma unroll
        for (int nj = 0; nj < 4; ++nj)
          acc[mi][nj] = __builtin_amdgcn_mfma_f32_16x16x32_bf16(af[mi], bfr[nj], acc[mi][nj], 0, 0, 0);
    }
  }
#pragma unroll
  for (int mi = 0; mi < 4; ++mi)
#pragma unroll
    for (int nj = 0; nj < 4; ++nj)
#pragma unroll
      for (int j = 0; j < 4; ++j) {
        const int row = m0 + wr * 64 + mi * 16 + lg * 4 + j;  // C/D: row=(lane>>4)*4+j
        const int col = n0 + wc * 64 + nj * 16 + lr;          //      col=lane&15
        if (OUTF32) ((float*)Cptr)[(size_t)row * N + col] = acc[mi][nj][j];
        else ((unsigned short*)Cptr)[(size_t)row * N + col] = f2bf(acc[mi][nj][j]);
      }
}

// ------- RoPE + pack Q,K to [bh][T][64]; Q pre-scaled by log2e/sqrt(D) -------
__global__ __launch_bounds__(256) void rope_pack_kernel(const unsigned short* __restrict__ QKV,
                                                        unsigned short* __restrict__ Qp,
                                                        unsigned short* __restrict__ Kp) {
  const int tt = blockIdx.x, bh = blockIdx.y;
  const int b = bh >> 4, h = bh & 15;
  const int tid = threadIdx.x;
  const int half = tid >> 7;           // 0=q, 1=k
  const int r = (tid >> 1) & 63;
  const int d0 = (tid & 1) * 16;
  const int t = tt * 64 + r;
  const unsigned short* src = QKV + (size_t)(b * T_ + t) * N3_ + half * C_ + h * D_;
  ushortx8 lo0 = *(const ushortx8*)(src + d0);
  ushortx8 lo1 = *(const ushortx8*)(src + d0 + 8);
  ushortx8 hi0 = *(const ushortx8*)(src + d0 + 32);
  ushortx8 hi1 = *(const ushortx8*)(src + d0 + 40);
  ushortx8 olo0, olo1, ohi0, ohi1;
  // 1/sqrt(64) * log2(e) folded into q so attn softmax can use exp2 directly
  const float scale = half ? 1.0f : 0.18033688011112042f;
  const float tf = (float)t;
#pragma unroll
  for (int jj = 0; jj < 16; ++jj) {
    const int d = d0 + jj;
    // inv_freq = 10000^(-d/32) = 2^(-d*log2(10000)/32)
    const float invf = exp2f((float)d * -0.41524101186092036f);
    const float ang = tf * invf;
    const float c = cosf(ang), s = sinf(ang);
    const float xl = bf2f(jj < 8 ? lo0[jj] : lo1[jj - 8]);
    const float xh = bf2f(jj < 8 ? hi0[jj] : hi1[jj - 8]);
    const unsigned short rl = f2bf((xl * c - xh * s) * scale);
    const unsigned short rh = f2bf((xh * c + xl * s) * scale);
    if (jj < 8) { olo0[jj] = rl; ohi0[jj] = rh; }
    else        { olo1[jj - 8] = rl; ohi1[jj - 8] = rh; }
  }
  unsigned short* dst = (half ? Kp : Qp) + ((size_t)bh * T_ + t) * D_;
  *(ushortx8*)(dst + d0) = olo0;
  *(ushortx8*)(dst + d0 + 8) = olo1;
  *(ushortx8*)(dst + d0 + 32) = ohi0;
  *(ushortx8*)(dst + d0 + 40) = ohi1;
}

// ---------------- V transpose: qkv v-cols -> Vt[bh][64][T] ----------------
__global__ __launch_bounds__(256) void vtrans_kernel(const unsigned short* __restrict__ QKV,
                                                     unsigned short* __restrict__ Vt) {
  __shared__ unsigned short tile[64][72];
  const int tt = blockIdx.x, bh = blockIdx.y;
  const int b = bh >> 4, h = bh & 15;
  const int tid = threadIdx.x;
  {
    const int r = tid >> 2, seg = tid & 3;
    const unsigned short* src = QKV + (size_t)(b * T_ + tt * 64 + r) * N3_ + 2 * C_ + h * D_ + seg * 16;
    *(ushortx8*)(&tile[r][seg * 16]) = *(const ushortx8*)(src);
    *(ushortx8*)(&tile[r][seg * 16 + 8]) = *(const ushortx8*)(src + 8);
  }
  __syncthreads();
  {
    const int d = tid >> 2, ts = tid & 3;
    ushortx8 o0, o1;
#pragma unroll
    for (int i = 0; i < 8; ++i) { o0[i] = tile[ts * 16 + i][d]; o1[i] = tile[ts * 16 + 8 + i][d]; }
    unsigned short* dst = Vt + ((size_t)bh * D_ + d) * T_ + tt * 64 + ts * 16;
    *(ushortx8*)(dst) = o0;
    *(ushortx8*)(dst + 8) = o1;
  }
}

// -------- causal flash attention v7: mirrored strips + counted-vmcnt staging --------
__global__ __launch_bounds__(256, 2) void attn7_kernel(const unsigned short* __restrict__ Qp,
                                                       const unsigned short* __restrict__ Kp,
                                                       const unsigned short* __restrict__ Vt,
                                                       unsigned short* __restrict__ Ob) {
  __shared__ unsigned short Klds[3][64 * 64];   // [buf][kv][d]   8KB each
  __shared__ unsigned short Vlds[3][64 * 64];   // [buf][d][kv]   8KB each
  const int tid = threadIdx.x, w = tid >> 6, l = tid & 63;
  const int lq = l & 31, hi = l >> 5;
  const int swz = lq & 7;
  const int bid = blockIdx.x;
  const int bh = bid & 31;                      // same head -> same XCD (bid%8)
  const int pp = bid >> 5;                      // 0..15
  const int p = (pp < 8) ? pp : 23 - pp;        // round-robin pairs: p1+p2=15; longest first
  const int s = (w < 2) ? (2 * p + w) : (62 - 2 * p + (w - 2));
  const int q0 = s * 32;
  const int ntiles = 32 - p;                    // kv tiles needed by strip 63-2p
  const size_t koff = (size_t)bh * T_ * D_;
  const unsigned short* Kb = Kp + koff;
  const unsigned short* Vb = Vt + (size_t)bh * D_ * T_;

  const int lr8 = l >> 3;               // staging: row within 8-row chunk
  const int lc8 = (l & 7) ^ lr8;        // pre-swizzled source 16B slot

  // Q B-frags: lane holds Q[q0+lq][ds*16 + hi*8 + j]
  bf16x8 qf[4];
  {
    const unsigned short* qp = Qp + koff + (size_t)(q0 + lq) * D_ + hi * 8;
#pragma unroll
    for (int ds = 0; ds < 4; ++ds) qf[ds] = *(const bf16x8*)(qp + ds * 16);
  }
  f32x16 o0, o1;
#pragma unroll
  for (int r = 0; r < 16; ++r) { o0[r] = 0.f; o1[r] = 0.f; }
  float m = -3.0e38f, lden = 0.f;

  // prologue: stage tile 0 into buf 0 (wave w stages chunks 2w, 2w+1)
#pragma unroll
  for (int i = 0; i < 2; ++i) {
    const int c = w * 2 + i;
    gload_lds16(Kb + (size_t)(c * 8 + lr8) * D_ + lc8 * 8, &Klds[0][c * 512]);
    gload_lds16(Vb + (size_t)(c * 8 + lr8) * T_ + lc8 * 8, &Vlds[0][c * 512]);
  }

  for (int kt = 0; kt < ntiles; ++kt) {
    const int cur = kt % 3;
    const int nxt = (kt + 1) % 3;
    // issue next-tile loads (clamped: last iter re-stages into an unread buf)
    const int ktn = (kt + 1 < ntiles) ? kt + 1 : kt;
    const int kvn = ktn * 64;
#pragma unroll
    for (int i = 0; i < 2; ++i) {
      const int c = w * 2 + i;
      gload_lds16(Kb + (size_t)(kvn + c * 8 + lr8) * D_ + lc8 * 8, &Klds[nxt][c * 512]);
      gload_lds16(Vb + (size_t)(c * 8 + lr8) * T_ + kvn + lc8 * 8, &Vlds[nxt][c * 512]);
    }
    // tile kt's 4 loads land (leave next tile's 4 in flight), then sync waves
    asm volatile("s_waitcnt vmcnt(4)" ::: "memory");
    __builtin_amdgcn_s_barrier();
    __builtin_amdgcn_sched_barrier(0);

    const int kv0 = kt * 64;
    if (kv0 <= q0 + 31) {   // wave-uniform: tile intersects causal range
      const unsigned short* KL = &Klds[cur][0];
      const unsigned short* VL = &Vlds[cur][0];
      // S^T = K . Q^T over d=64, two 32-kv groups
      f32x16 acc0, acc1;
#pragma unroll
      for (int r = 0; r < 16; ++r) { acc0[r] = 0.f; acc1[r] = 0.f; }
      __builtin_amdgcn_s_setprio(1);
#pragma unroll
      for (int ds = 0; ds < 4; ++ds) {
        const int slot = ((ds * 2 + hi) ^ swz) * 8;
        const bf16x8 kf0 = *(const bf16x8*)(&KL[(lq) * 64 + slot]);
        const bf16x8 kf1 = *(const bf16x8*)(&KL[(32 + lq) * 64 + slot]);
        acc0 = __builtin_amdgcn_mfma_f32_32x32x16_bf16(kf0, qf[ds], acc0, 0, 0, 0);
        acc1 = __builtin_amdgcn_mfma_f32_32x32x16_bf16(kf1, qf[ds], acc1, 0, 0, 0);
      }
      __builtin_amdgcn_s_setprio(0);
      if (kv0 + 63 > q0) {   // diagonal tile(s): mask kv_global > q_global
        const int thr0 = q0 + lq - kv0;
        const int thr1 = thr0 - 32;
#pragma unroll
        for (int r = 0; r < 16; ++r) {
          const int kvloc = (r & 3) + 8 * (r >> 2) + 4 * hi;
          if (kvloc > thr0) acc0[r] = -3.0e38f;
          if (kvloc > thr1) acc1[r] = -3.0e38f;
        }
      }
      // in-lane max over 32 + cross-half permlane swap
      float mx[8];
#pragma unroll
      for (int i = 0; i < 8; ++i)
        mx[i] = fmaxf(fmaxf(acc0[i], acc0[i + 8]), fmaxf(acc1[i], acc1[i + 8]));
#pragma unroll
      for (int i = 0; i < 4; ++i) mx[i] = fmaxf(mx[i], mx[i + 4]);
      const float mloc = fmaxf(fmaxf(mx[0], mx[1]), fmaxf(mx[2], mx[3]));
      const uintx2 mp = __builtin_amdgcn_permlane32_swap(__float_as_uint(mloc), __float_as_uint(mloc), false, false);
      const float pm = fmaxf(__uint_as_float(mp.x), __uint_as_float(mp.y));
      // defer-max (T13): rescale only when max grew by > 8
      const bool grow = pm > m + 8.0f;
      if (__any(grow)) {
        const float mn = grow ? pm : m;
        const float alpha = __builtin_amdgcn_exp2f(m - mn);
        m = mn;
        lden *= alpha;
#pragma unroll
        for (int r = 0; r < 16; ++r) { o0[r] *= alpha; o1[r] *= alpha; }
      }
      float p0[16], p1[16];
#pragma unroll
      for (int r = 0; r < 16; ++r) {
        p0[r] = __builtin_amdgcn_exp2f(acc0[r] - m);
        p1[r] = __builtin_amdgcn_exp2f(acc1[r] - m);
      }
      // P -> B-frags (T12): cvt_pk pairs, permlane32_swap x-hi <-> y-lo
      unsigned W0 = cvtpk_bf16(p0[0], p0[1]), W1 = cvtpk_bf16(p0[2], p0[3]);
      unsigned W2 = cvtpk_bf16(p0[4], p0[5]), W3 = cvtpk_bf16(p0[6], p0[7]);
      uintx2 Aa = __builtin_amdgcn_permlane32_swap(W0, W2, false, false);
      uintx2 Ab = __builtin_amdgcn_permlane32_swap(W1, W3, false, false);
      union { unsigned u[4]; bf16x8 v; } pfa0 = {{Aa.x, Ab.x, Aa.y, Ab.y}};
      W0 = cvtpk_bf16(p0[8], p0[9]);   W1 = cvtpk_bf16(p0[10], p0[11]);
      W2 = cvtpk_bf16(p0[12], p0[13]); W3 = cvtpk_bf16(p0[14], p0[15]);
      Aa = __builtin_amdgcn_permlane32_swap(W0, W2, false, false);
      Ab = __builtin_amdgcn_permlane32_swap(W1, W3, false, false);
      union { unsigned u[4]; bf16x8 v; } pfa1 = {{Aa.x, Ab.x, Aa.y, Ab.y}};
      W0 = cvtpk_bf16(p1[0], p1[1]);   W1 = cvtpk_bf16(p1[2], p1[3]);
      W2 = cvtpk_bf16(p1[4], p1[5]);   W3 = cvtpk_bf16(p1[6], p1[7]);
      Aa = __builtin_amdgcn_permlane32_swap(W0, W2, false, false);
      Ab = __builtin_amdgcn_permlane32_swap(W1, W3, false, false);
      union { unsigned u[4]; bf16x8 v; } pfb0 = {{Aa.x, Ab.x, Aa.y, Ab.y}};
      W0 = cvtpk_bf16(p1[8], p1[9]);   W1 = cvtpk_bf16(p1[10], p1[11]);
      W2 = cvtpk_bf16(p1[12], p1[13]); W3 = cvtpk_bf16(p1[14], p1[15]);
      Aa = __builtin_amdgcn_permlane32_swap(W0, W2, false, false);
      Ab = __builtin_amdgcn_permlane32_swap(W1, W3, false, false);
      union { unsigned u[4]; bf16x8 v; } pfb1 = {{Aa.x, Ab.x, Aa.y, Ab.y}};

      // O^T += V^T . P^T  (kv slices: 0-15=pfa0, 16-31=pfa1, 32-47=pfb0, 48-63=pfb1)
      __builtin_amdgcn_s_setprio(1);
#pragma unroll
      for (int dt = 0; dt < 2; ++dt) {
        const int rowb = (dt * 32 + lq) * 64;
        const bf16x8 vf0 = *(const bf16x8*)(&VL[rowb + ((0 * 2 + hi) ^ swz) * 8]);
        const bf16x8 vf1 = *(const bf16x8*)(&VL[rowb + ((1 * 2 + hi) ^ swz) * 8]);
        const bf16x8 vf2 = *(const bf16x8*)(&VL[rowb + ((2 * 2 + hi) ^ swz) * 8]);
        const bf16x8 vf3 = *(const bf16x8*)(&VL[rowb + ((3 * 2 + hi) ^ swz) * 8]);
        if (dt == 0) {
          o0 = __builtin_amdgcn_mfma_f32_32x32x16_bf16(vf0, pfa0.v, o0, 0, 0, 0);
          o0 = __builtin_amdgcn_mfma_f32_32x32x16_bf16(vf1, pfa1.v, o0, 0, 0, 0);
          o0 = __builtin_amdgcn_mfma_f32_32x32x16_bf16(vf2, pfb0.v, o0, 0, 0, 0);
          o0 = __builtin_amdgcn_mfma_f32_32x32x16_bf16(vf3, pfb1.v, o0, 0, 0, 0);
        } else {
          o1 = __builtin_amdgcn_mfma_f32_32x32x16_bf16(vf0, pfa0.v, o1, 0, 0, 0);
          o1 = __builtin_amdgcn_mfma_f32_32x32x16_bf16(vf1, pfa1.v, o1, 0, 0, 0);
          o1 = __builtin_amdgcn_mfma_f32_32x32x16_bf16(vf2, pfb0.v, o1, 0, 0, 0);
          o1 = __builtin_amdgcn_mfma_f32_32x32x16_bf16(vf3, pfb1.v, o1, 0, 0, 0);
        }
      }
      __builtin_amdgcn_s_setprio(0);
      // lsum trees (overlaps PV on VALU pipe)
      float sm[8];
#pragma unroll
      for (int i = 0; i < 8; ++i) sm[i] = (p0[i] + p0[i + 8]) + (p1[i] + p1[i + 8]);
#pragma unroll
      for (int i = 0; i < 4; ++i) sm[i] = sm[i] + sm[i + 4];
      const float sloc = (sm[0] + sm[1]) + (sm[2] + sm[3]);
      const uintx2 sp = __builtin_amdgcn_permlane32_swap(__float_as_uint(sloc), __float_as_uint(sloc), false, false);
      lden += __uint_as_float(sp.x) + __uint_as_float(sp.y);
    }
  }
  asm volatile("s_waitcnt vmcnt(0)" ::: "memory");   // drain trailing prefetch

  // epilogue: lane holds q=q0+lq, d = dt*32 + rq*8 + 4*hi + i
  const float rl = __builtin_amdgcn_rcpf(lden);
  const int b = bh >> 4, hh = bh & 15;
  unsigned short* orow = Ob + (size_t)(b * T_ + q0 + lq) * C_ + hh * D_ + 4 * hi;
#pragma unroll
  for (int rq = 0; rq < 4; ++rq) {
    ushortx4 ov0, ov1;
#pragma unroll
    for (int i = 0; i < 4; ++i) {
      ov0[i] = f2bf(o0[rq * 4 + i] * rl);
      ov1[i] = f2bf(o1[rq * 4 + i] * rl);
    }
    *(ushortx4*)(orow + rq * 8) = ov0;
    *(ushortx4*)(orow + 32 + rq * 8) = ov1;
  }
}

// ---------------- launch ----------------
extern "C" void kernel_launch(void* const* d_in, const int* in_sizes, int n_in,
                              void* d_out, int out_size, void* d_ws, size_t ws_size,
                              hipStream_t stream) {
  const float* x = (const float*)d_in[0];
  const float* Wqkv = (const float*)d_in[1];
  const float* Wout = (const float*)d_in[2];
  float* out = (float*)d_out;
  char* ws = (char*)d_ws;
  // workspace layout (72 MiB total)
  unsigned short* Xb    = (unsigned short*)(ws);                  //  8 MiB [4096][1024]
  unsigned short* WqkvT = (unsigned short*)(ws + (8ull << 20));   //  6 MiB [3072][1024]
  unsigned short* WoutT = (unsigned short*)(ws + (14ull << 20));  //  2 MiB [1024][1024]
  unsigned short* QKVb  = (unsigned short*)(ws + (16ull << 20));  // 24 MiB [4096][3072]
  unsigned short* Qp    = (unsigned short*)(ws + (40ull << 20));  //  8 MiB [32][2048][64]
  unsigned short* Kp    = (unsigned short*)(ws + (48ull << 20));  //  8 MiB
  unsigned short* Vt    = (unsigned short*)(ws + (56ull << 20));  //  8 MiB [32][64][2048]
  unsigned short* Ob    = (unsigned short*)(ws + (64ull << 20));  //  8 MiB [4096][1024]

  cvt_x_kernel<<<4096, 256, 0, stream>>>(x, Xb);
  tconv_kernel<<<dim3(N3_ / 32, C_ / 32), 256, 0, stream>>>(Wqkv, WqkvT, C_, N3_);
  tconv_kernel<<<dim3(C_ / 32, C_ / 32), 256, 0, stream>>>(Wout, WoutT, C_, C_);
  gemm256_kernel<<<(B_ * T_ / 256) * (N3_ / 256), 512, 0, stream>>>(
      Xb, WqkvT, QKVb, B_ * T_, N3_, C_);
  rope_pack_kernel<<<dim3(T_ / 64, B_ * H_), 256, 0, stream>>>(QKVb, Qp, Kp);
  vtrans_kernel<<<dim3(T_ / 64, B_ * H_), 256, 0, stream>>>(QKVb, Vt);
  attn7_kernel<<<512, 256, 0, stream>>>(Qp, Kp, Vt, Ob);
  gemm_bt_kernel<1><<<dim3(C_ / 128, (B_ * T_) / 128), 256, 0, stream>>>(
      Ob, WoutT, out, B_ * T_, C_, C_);
}

// Round 11
// 118.957 us; speedup vs baseline: 1.1746x; 1.1746x over previous
//
#include <hip/hip_runtime.h>

// Problem: CausalSelfAttention  B=2 T=2048 C=1024 H=16 D=64, fp32 in/out.
// Pipeline: prep(cvt+tconv+tconv fused) -> GEMM1(128^2 bf16) -> rope+vtrans(fused)
//           -> attn7 -> GEMM2(128^2, fp32 out).   5 launches total.

#define B_  2
#define T_  2048
#define C_  1024
#define H_  16
#define D_  64
#define N3_ 3072

typedef unsigned short ushortx8 __attribute__((ext_vector_type(8)));
typedef unsigned short ushortx4 __attribute__((ext_vector_type(4)));
typedef short bf16x8 __attribute__((ext_vector_type(8)));
typedef float f32x4 __attribute__((ext_vector_type(4)));
typedef float f32x16 __attribute__((ext_vector_type(16)));
typedef unsigned int uintx2 __attribute__((ext_vector_type(2)));

__device__ __forceinline__ unsigned short f2bf(float f) {
  union { float f; unsigned u; } v; v.f = f;
  unsigned r = v.u + 0x7FFFu + ((v.u >> 16) & 1u);   // RNE
  return (unsigned short)(r >> 16);
}
__device__ __forceinline__ float bf2f(unsigned short h) {
  union { unsigned u; float f; } v; v.u = ((unsigned)h) << 16;
  return v.f;
}
// pack two f32 -> 2xbf16 in one u32 (no builtin exists; m240)
__device__ __forceinline__ unsigned cvtpk_bf16(float lo, float hi) {
  unsigned r; asm("v_cvt_pk_bf16_f32 %0, %1, %2" : "=v"(r) : "v"(lo), "v"(hi));
  return r;
}
// async global->LDS, 16B per lane; dst must be wave-uniform (HW adds lane*16)
__device__ __forceinline__ void gload_lds16(const void* g, void* l) {
  __builtin_amdgcn_global_load_lds((const __attribute__((address_space(1))) void*)g,
                                   (__attribute__((address_space(3))) void*)l,
                                   16, 0, 0);
}

// ---- fused prep: blocks [0,4096) cvt x->bf16; [4096,7168) tconv Wqkv; [7168,8192) tconv Wout
__global__ __launch_bounds__(256) void prep_kernel(const float* __restrict__ x,
                                                   unsigned short* __restrict__ Xb,
                                                   const float* __restrict__ Wqkv,
                                                   unsigned short* __restrict__ WqkvT,
                                                   const float* __restrict__ Wout,
                                                   unsigned short* __restrict__ WoutT) {
  __shared__ float tile[32][33];
  const int bid = blockIdx.x;
  if (bid < 4096) {
    size_t i = ((size_t)bid * 256 + threadIdx.x) * 4;
    const float4 v = *(const float4*)(x + i);
    ushortx4 o;
    o[0] = f2bf(v.x); o[1] = f2bf(v.y); o[2] = f2bf(v.z); o[3] = f2bf(v.w);
    *(ushortx4*)(Xb + i) = o;
    return;
  }
  const float* W;
  unsigned short* WT;
  int K, N, n0, k0;
  if (bid < 7168) {
    const int idx = bid - 4096;
    W = Wqkv; WT = WqkvT; K = C_; N = N3_;
    n0 = (idx % (N3_ / 32)) * 32; k0 = (idx / (N3_ / 32)) * 32;
  } else {
    const int idx = bid - 7168;
    W = Wout; WT = WoutT; K = C_; N = C_;
    n0 = (idx % (C_ / 32)) * 32; k0 = (idx / (C_ / 32)) * 32;
  }
  const int tx = threadIdx.x & 31, ty = threadIdx.x >> 5;
#pragma unroll
  for (int i = 0; i < 4; ++i)
    tile[ty + i * 8][tx] = W[(size_t)(k0 + ty + i * 8) * N + n0 + tx];
  __syncthreads();
#pragma unroll
  for (int i = 0; i < 4; ++i)
    WT[(size_t)(n0 + ty + i * 8) * K + k0 + tx] = f2bf(tile[tx][ty + i * 8]);
}

// ---------------- GEMM: C[M][N] = A[M][K] * BT[N][K]^T (bf16 MFMA) ----------------
// 128x128 tile, BK=64, 4 waves (each 64x64), global_load_lds w/ XOR-swizzled source.
template <int OUTF32>
__global__ __launch_bounds__(256) void gemm_bt_kernel(const unsigned short* __restrict__ A,
                                                      const unsigned short* __restrict__ BT,
                                                      void* __restrict__ Cptr,
                                                      int M, int N, int K) {
  __shared__ unsigned short Alds[128 * 64];
  __shared__ unsigned short Blds[128 * 64];
  const int tid = threadIdx.x;
  const int w = tid >> 6, l = tid & 63;
  const int wr = w >> 1, wc = w & 1;
  const int lg = l >> 4, lr = l & 15;
  const int m0 = blockIdx.y * 128, n0 = blockIdx.x * 128;
  const int lr8 = l >> 3;                 // row within 8-row chunk
  const int lc8 = (l & 7) ^ lr8;          // pre-swizzled source col16 (T2 st-style)

  f32x4 acc[4][4];
#pragma unroll
  for (int i = 0; i < 4; ++i)
#pragma unroll
    for (int j = 0; j < 4; ++j) acc[i][j] = f32x4{0.f, 0.f, 0.f, 0.f};

  for (int k0 = 0; k0 < K; k0 += 64) {
    __syncthreads();
#pragma unroll
    for (int i = 0; i < 4; ++i) {
      const int ch = w * 4 + i;           // 16 chunks of 1024B per tile
      gload_lds16(A + (size_t)(m0 + ch * 8 + lr8) * K + k0 + lc8 * 8, &Alds[ch * 512]);
      gload_lds16(BT + (size_t)(n0 + ch * 8 + lr8) * K + k0 + lc8 * 8, &Blds[ch * 512]);
    }
    __syncthreads();
#pragma unroll
    for (int kc = 0; kc < 2; ++kc) {
      bf16x8 af[4], bfr[4];
#pragma unroll
      for (int mi = 0; mi < 4; ++mi) {
        const int row = wr * 64 + mi * 16 + lr;
        const int c16 = (kc * 4 + lg) ^ (row & 7);
        af[mi] = *(const bf16x8*)(&Alds[row * 64 + c16 * 8]);
      }
#pragma unroll
      for (int nj = 0; nj < 4; ++nj) {
        const int row = wc * 64 + nj * 16 + lr;
        const int c16 = (kc * 4 + lg) ^ (row & 7);
        bfr[nj] = *(const bf16x8*)(&Blds[row * 64 + c16 * 8]);
      }
#pragma unroll
      for (int mi = 0; mi < 4; ++mi)
#pragma unroll
        for (int nj = 0; nj < 4; ++nj)
          acc[mi][nj] = __builtin_amdgcn_mfma_f32_16x16x32_bf16(af[mi], bfr[nj], acc[mi][nj], 0, 0, 0);
    }
  }
#pragma unroll
  for (int mi = 0; mi < 4; ++mi)
#pragma unroll
    for (int nj = 0; nj < 4; ++nj)
#pragma unroll
      for (int j = 0; j < 4; ++j) {
        const int row = m0 + wr * 64 + mi * 16 + lg * 4 + j;  // C/D: row=(lane>>4)*4+j
        const int col = n0 + wc * 64 + nj * 16 + lr;          //      col=lane&15
        if (OUTF32) ((float*)Cptr)[(size_t)row * N + col] = acc[mi][nj][j];
        else ((unsigned short*)Cptr)[(size_t)row * N + col] = f2bf(acc[mi][nj][j]);
      }
}

// ---- fused RoPE-pack (z=0) + V-transpose (z=1) ----
__global__ __launch_bounds__(256) void rope_vtrans_kernel(const unsigned short* __restrict__ QKV,
                                                          unsigned short* __restrict__ Qp,
                                                          unsigned short* __restrict__ Kp,
                                                          unsigned short* __restrict__ Vt) {
  __shared__ unsigned short tile[64][72];
  const int tt = blockIdx.x, bh = blockIdx.y;
  const int b = bh >> 4, h = bh & 15;
  const int tid = threadIdx.x;
  if (blockIdx.z == 0) {
    // RoPE + pack Q,K to [bh][T][64]; Q pre-scaled by log2e/sqrt(D)
    const int half = tid >> 7;           // 0=q, 1=k
    const int r = (tid >> 1) & 63;
    const int d0 = (tid & 1) * 16;
    const int t = tt * 64 + r;
    const unsigned short* src = QKV + (size_t)(b * T_ + t) * N3_ + half * C_ + h * D_;
    ushortx8 lo0 = *(const ushortx8*)(src + d0);
    ushortx8 lo1 = *(const ushortx8*)(src + d0 + 8);
    ushortx8 hi0 = *(const ushortx8*)(src + d0 + 32);
    ushortx8 hi1 = *(const ushortx8*)(src + d0 + 40);
    ushortx8 olo0, olo1, ohi0, ohi1;
    const float scale = half ? 1.0f : 0.18033688011112042f;
    const float tf = (float)t;
#pragma unroll
    for (int jj = 0; jj < 16; ++jj) {
      const int d = d0 + jj;
      const float invf = exp2f((float)d * -0.41524101186092036f);
      const float ang = tf * invf;
      const float c = cosf(ang), s = sinf(ang);
      const float xl = bf2f(jj < 8 ? lo0[jj] : lo1[jj - 8]);
      const float xh = bf2f(jj < 8 ? hi0[jj] : hi1[jj - 8]);
      const unsigned short rl = f2bf((xl * c - xh * s) * scale);
      const unsigned short rh = f2bf((xh * c + xl * s) * scale);
      if (jj < 8) { olo0[jj] = rl; ohi0[jj] = rh; }
      else        { olo1[jj - 8] = rl; ohi1[jj - 8] = rh; }
    }
    unsigned short* dst = (half ? Kp : Qp) + ((size_t)bh * T_ + t) * D_;
    *(ushortx8*)(dst + d0) = olo0;
    *(ushortx8*)(dst + d0 + 8) = olo1;
    *(ushortx8*)(dst + d0 + 32) = ohi0;
    *(ushortx8*)(dst + d0 + 40) = ohi1;
  } else {
    // V transpose: qkv v-cols -> Vt[bh][64][T]
    {
      const int r = tid >> 2, seg = tid & 3;
      const unsigned short* src = QKV + (size_t)(b * T_ + tt * 64 + r) * N3_ + 2 * C_ + h * D_ + seg * 16;
      *(ushortx8*)(&tile[r][seg * 16]) = *(const ushortx8*)(src);
      *(ushortx8*)(&tile[r][seg * 16 + 8]) = *(const ushortx8*)(src + 8);
    }
    __syncthreads();
    {
      const int d = tid >> 2, ts = tid & 3;
      ushortx8 o0, o1;
#pragma unroll
      for (int i = 0; i < 8; ++i) { o0[i] = tile[ts * 16 + i][d]; o1[i] = tile[ts * 16 + 8 + i][d]; }
      unsigned short* dst = Vt + ((size_t)bh * D_ + d) * T_ + tt * 64 + ts * 16;
      *(ushortx8*)(dst) = o0;
      *(ushortx8*)(dst + 8) = o1;
    }
  }
}

// -------- causal flash attention v7: mirrored strips + counted-vmcnt staging --------
__global__ __launch_bounds__(256, 2) void attn7_kernel(const unsigned short* __restrict__ Qp,
                                                       const unsigned short* __restrict__ Kp,
                                                       const unsigned short* __restrict__ Vt,
                                                       unsigned short* __restrict__ Ob) {
  __shared__ unsigned short Klds[3][64 * 64];   // [buf][kv][d]   8KB each
  __shared__ unsigned short Vlds[3][64 * 64];   // [buf][d][kv]   8KB each
  const int tid = threadIdx.x, w = tid >> 6, l = tid & 63;
  const int lq = l & 31, hi = l >> 5;
  const int swz = lq & 7;
  const int bid = blockIdx.x;
  const int bh = bid & 31;                      // same head -> same XCD (bid%8)
  const int pp = bid >> 5;                      // 0..15
  const int p = (pp < 8) ? pp : 23 - pp;        // round-robin pairs: p1+p2=15; longest first
  const int s = (w < 2) ? (2 * p + w) : (62 - 2 * p + (w - 2));
  const int q0 = s * 32;
  const int ntiles = 32 - p;                    // kv tiles needed by strip 63-2p
  const size_t koff = (size_t)bh * T_ * D_;
  const unsigned short* Kb = Kp + koff;
  const unsigned short* Vb = Vt + (size_t)bh * D_ * T_;

  const int lr8 = l >> 3;               // staging: row within 8-row chunk
  const int lc8 = (l & 7) ^ lr8;        // pre-swizzled source 16B slot

  // Q B-frags: lane holds Q[q0+lq][ds*16 + hi*8 + j]
  bf16x8 qf[4];
  {
    const unsigned short* qp = Qp + koff + (size_t)(q0 + lq) * D_ + hi * 8;
#pragma unroll
    for (int ds = 0; ds < 4; ++ds) qf[ds] = *(const bf16x8*)(qp + ds * 16);
  }
  f32x16 o0, o1;
#pragma unroll
  for (int r = 0; r < 16; ++r) { o0[r] = 0.f; o1[r] = 0.f; }
  float m = -3.0e38f, lden = 0.f;

  // prologue: stage tile 0 into buf 0 (wave w stages chunks 2w, 2w+1)
#pragma unroll
  for (int i = 0; i < 2; ++i) {
    const int c = w * 2 + i;
    gload_lds16(Kb + (size_t)(c * 8 + lr8) * D_ + lc8 * 8, &Klds[0][c * 512]);
    gload_lds16(Vb + (size_t)(c * 8 + lr8) * T_ + lc8 * 8, &Vlds[0][c * 512]);
  }

  for (int kt = 0; kt < ntiles; ++kt) {
    const int cur = kt % 3;
    const int nxt = (kt + 1) % 3;
    // issue next-tile loads (clamped: last iter re-stages into an unread buf)
    const int ktn = (kt + 1 < ntiles) ? kt + 1 : kt;
    const int kvn = ktn * 64;
#pragma unroll
    for (int i = 0; i < 2; ++i) {
      const int c = w * 2 + i;
      gload_lds16(Kb + (size_t)(kvn + c * 8 + lr8) * D_ + lc8 * 8, &Klds[nxt][c * 512]);
      gload_lds16(Vb + (size_t)(c * 8 + lr8) * T_ + kvn + lc8 * 8, &Vlds[nxt][c * 512]);
    }
    // tile kt's 4 loads land (leave next tile's 4 in flight), then sync waves
    asm volatile("s_waitcnt vmcnt(4)" ::: "memory");
    __builtin_amdgcn_s_barrier();
    __builtin_amdgcn_sched_barrier(0);

    const int kv0 = kt * 64;
    if (kv0 <= q0 + 31) {   // wave-uniform: tile intersects causal range
      const unsigned short* KL = &Klds[cur][0];
      const unsigned short* VL = &Vlds[cur][0];
      // S^T = K . Q^T over d=64, two 32-kv groups
      f32x16 acc0, acc1;
#pragma unroll
      for (int r = 0; r < 16; ++r) { acc0[r] = 0.f; acc1[r] = 0.f; }
      __builtin_amdgcn_s_setprio(1);
#pragma unroll
      for (int ds = 0; ds < 4; ++ds) {
        const int slot = ((ds * 2 + hi) ^ swz) * 8;
        const bf16x8 kf0 = *(const bf16x8*)(&KL[(lq) * 64 + slot]);
        const bf16x8 kf1 = *(const bf16x8*)(&KL[(32 + lq) * 64 + slot]);
        acc0 = __builtin_amdgcn_mfma_f32_32x32x16_bf16(kf0, qf[ds], acc0, 0, 0, 0);
        acc1 = __builtin_amdgcn_mfma_f32_32x32x16_bf16(kf1, qf[ds], acc1, 0, 0, 0);
      }
      __builtin_amdgcn_s_setprio(0);
      if (kv0 + 63 > q0) {   // diagonal tile(s): mask kv_global > q_global
        const int thr0 = q0 + lq - kv0;
        const int thr1 = thr0 - 32;
#pragma unroll
        for (int r = 0; r < 16; ++r) {
          const int kvloc = (r & 3) + 8 * (r >> 2) + 4 * hi;
          if (kvloc > thr0) acc0[r] = -3.0e38f;
          if (kvloc > thr1) acc1[r] = -3.0e38f;
        }
      }
      // in-lane max over 32 + cross-half permlane swap
      float mx[8];
#pragma unroll
      for (int i = 0; i < 8; ++i)
        mx[i] = fmaxf(fmaxf(acc0[i], acc0[i + 8]), fmaxf(acc1[i], acc1[i + 8]));
#pragma unroll
      for (int i = 0; i < 4; ++i) mx[i] = fmaxf(mx[i], mx[i + 4]);
      const float mloc = fmaxf(fmaxf(mx[0], mx[1]), fmaxf(mx[2], mx[3]));
      const uintx2 mp = __builtin_amdgcn_permlane32_swap(__float_as_uint(mloc), __float_as_uint(mloc), false, false);
      const float pm = fmaxf(__uint_as_float(mp.x), __uint_as_float(mp.y));
      // defer-max (T13): rescale only when max grew by > 8
      const bool grow = pm > m + 8.0f;
      if (__any(grow)) {
        const float mn = grow ? pm : m;
        const float alpha = __builtin_amdgcn_exp2f(m - mn);
        m = mn;
        lden *= alpha;
#pragma unroll
        for (int r = 0; r < 16; ++r) { o0[r] *= alpha; o1[r] *= alpha; }
      }
      float p0[16], p1[16];
#pragma unroll
      for (int r = 0; r < 16; ++r) {
        p0[r] = __builtin_amdgcn_exp2f(acc0[r] - m);
        p1[r] = __builtin_amdgcn_exp2f(acc1[r] - m);
      }
      // P -> B-frags (T12): cvt_pk pairs, permlane32_swap x-hi <-> y-lo
      unsigned W0 = cvtpk_bf16(p0[0], p0[1]), W1 = cvtpk_bf16(p0[2], p0[3]);
      unsigned W2 = cvtpk_bf16(p0[4], p0[5]), W3 = cvtpk_bf16(p0[6], p0[7]);
      uintx2 Aa = __builtin_amdgcn_permlane32_swap(W0, W2, false, false);
      uintx2 Ab = __builtin_amdgcn_permlane32_swap(W1, W3, false, false);
      union { unsigned u[4]; bf16x8 v; } pfa0 = {{Aa.x, Ab.x, Aa.y, Ab.y}};
      W0 = cvtpk_bf16(p0[8], p0[9]);   W1 = cvtpk_bf16(p0[10], p0[11]);
      W2 = cvtpk_bf16(p0[12], p0[13]); W3 = cvtpk_bf16(p0[14], p0[15]);
      Aa = __builtin_amdgcn_permlane32_swap(W0, W2, false, false);
      Ab = __builtin_amdgcn_permlane32_swap(W1, W3, false, false);
      union { unsigned u[4]; bf16x8 v; } pfa1 = {{Aa.x, Ab.x, Aa.y, Ab.y}};
      W0 = cvtpk_bf16(p1[0], p1[1]);   W1 = cvtpk_bf16(p1[2], p1[3]);
      W2 = cvtpk_bf16(p1[4], p1[5]);   W3 = cvtpk_bf16(p1[6], p1[7]);
      Aa = __builtin_amdgcn_permlane32_swap(W0, W2, false, false);
      Ab = __builtin_amdgcn_permlane32_swap(W1, W3, false, false);
      union { unsigned u[4]; bf16x8 v; } pfb0 = {{Aa.x, Ab.x, Aa.y, Ab.y}};
      W0 = cvtpk_bf16(p1[8], p1[9]);   W1 = cvtpk_bf16(p1[10], p1[11]);
      W2 = cvtpk_bf16(p1[12], p1[13]); W3 = cvtpk_bf16(p1[14], p1[15]);
      Aa = __builtin_amdgcn_permlane32_swap(W0, W2, false, false);
      Ab = __builtin_amdgcn_permlane32_swap(W1, W3, false, false);
      union { unsigned u[4]; bf16x8 v; } pfb1 = {{Aa.x, Ab.x, Aa.y, Ab.y}};

      // O^T += V^T . P^T  (kv slices: 0-15=pfa0, 16-31=pfa1, 32-47=pfb0, 48-63=pfb1)
      __builtin_amdgcn_s_setprio(1);
#pragma unroll
      for (int dt = 0; dt < 2; ++dt) {
        const int rowb = (dt * 32 + lq) * 64;
        const bf16x8 vf0 = *(const bf16x8*)(&VL[rowb + ((0 * 2 + hi) ^ swz) * 8]);
        const bf16x8 vf1 = *(const bf16x8*)(&VL[rowb + ((1 * 2 + hi) ^ swz) * 8]);
        const bf16x8 vf2 = *(const bf16x8*)(&VL[rowb + ((2 * 2 + hi) ^ swz) * 8]);
        const bf16x8 vf3 = *(const bf16x8*)(&VL[rowb + ((3 * 2 + hi) ^ swz) * 8]);
        if (dt == 0) {
          o0 = __builtin_amdgcn_mfma_f32_32x32x16_bf16(vf0, pfa0.v, o0, 0, 0, 0);
          o0 = __builtin_amdgcn_mfma_f32_32x32x16_bf16(vf1, pfa1.v, o0, 0, 0, 0);
          o0 = __builtin_amdgcn_mfma_f32_32x32x16_bf16(vf2, pfb0.v, o0, 0, 0, 0);
          o0 = __builtin_amdgcn_mfma_f32_32x32x16_bf16(vf3, pfb1.v, o0, 0, 0, 0);
        } else {
          o1 = __builtin_amdgcn_mfma_f32_32x32x16_bf16(vf0, pfa0.v, o1, 0, 0, 0);
          o1 = __builtin_amdgcn_mfma_f32_32x32x16_bf16(vf1, pfa1.v, o1, 0, 0, 0);
          o1 = __builtin_amdgcn_mfma_f32_32x32x16_bf16(vf2, pfb0.v, o1, 0, 0, 0);
          o1 = __builtin_amdgcn_mfma_f32_32x32x16_bf16(vf3, pfb1.v, o1, 0, 0, 0);
        }
      }
      __builtin_amdgcn_s_setprio(0);
      // lsum trees (overlaps PV on VALU pipe)
      float sm[8];
#pragma unroll
      for (int i = 0; i < 8; ++i) sm[i] = (p0[i] + p0[i + 8]) + (p1[i] + p1[i + 8]);
#pragma unroll
      for (int i = 0; i < 4; ++i) sm[i] = sm[i] + sm[i + 4];
      const float sloc = (sm[0] + sm[1]) + (sm[2] + sm[3]);
      const uintx2 sp = __builtin_amdgcn_permlane32_swap(__float_as_uint(sloc), __float_as_uint(sloc), false, false);
      lden += __uint_as_float(sp.x) + __uint_as_float(sp.y);
    }
  }
  asm volatile("s_waitcnt vmcnt(0)" ::: "memory");   // drain trailing prefetch

  // epilogue: lane holds q=q0+lq, d = dt*32 + rq*8 + 4*hi + i
  const float rl = __builtin_amdgcn_rcpf(lden);
  const int b = bh >> 4, hh = bh & 15;
  unsigned short* orow = Ob + (size_t)(b * T_ + q0 + lq) * C_ + hh * D_ + 4 * hi;
#pragma unroll
  for (int rq = 0; rq < 4; ++rq) {
    ushortx4 ov0, ov1;
#pragma unroll
    for (int i = 0; i < 4; ++i) {
      ov0[i] = f2bf(o0[rq * 4 + i] * rl);
      ov1[i] = f2bf(o1[rq * 4 + i] * rl);
    }
    *(ushortx4*)(orow + rq * 8) = ov0;
    *(ushortx4*)(orow + 32 + rq * 8) = ov1;
  }
}

// ---------------- launch ----------------
extern "C" void kernel_launch(void* const* d_in, const int* in_sizes, int n_in,
                              void* d_out, int out_size, void* d_ws, size_t ws_size,
                              hipStream_t stream) {
  const float* x = (const float*)d_in[0];
  const float* Wqkv = (const float*)d_in[1];
  const float* Wout = (const float*)d_in[2];
  float* out = (float*)d_out;
  char* ws = (char*)d_ws;
  // workspace layout (72 MiB total)
  unsigned short* Xb    = (unsigned short*)(ws);                  //  8 MiB [4096][1024]
  unsigned short* WqkvT = (unsigned short*)(ws + (8ull << 20));   //  6 MiB [3072][1024]
  unsigned short* WoutT = (unsigned short*)(ws + (14ull << 20));  //  2 MiB [1024][1024]
  unsigned short* QKVb  = (unsigned short*)(ws + (16ull << 20));  // 24 MiB [4096][3072]
  unsigned short* Qp    = (unsigned short*)(ws + (40ull << 20));  //  8 MiB [32][2048][64]
  unsigned short* Kp    = (unsigned short*)(ws + (48ull << 20));  //  8 MiB
  unsigned short* Vt    = (unsigned short*)(ws + (56ull << 20));  //  8 MiB [32][64][2048]
  unsigned short* Ob    = (unsigned short*)(ws + (64ull << 20));  //  8 MiB [4096][1024]

  prep_kernel<<<8192, 256, 0, stream>>>(x, Xb, Wqkv, WqkvT, Wout, WoutT);
  gemm_bt_kernel<0><<<dim3(N3_ / 128, (B_ * T_) / 128), 256, 0, stream>>>(
      Xb, WqkvT, QKVb, B_ * T_, N3_, C_);
  rope_vtrans_kernel<<<dim3(T_ / 64, B_ * H_, 2), 256, 0, stream>>>(QKVb, Qp, Kp, Vt);
  attn7_kernel<<<512, 256, 0, stream>>>(Qp, Kp, Vt, Ob);
  gemm_bt_kernel<1><<<dim3(C_ / 128, (B_ * T_) / 128), 256, 0, stream>>>(
      Ob, WoutT, out, B_ * T_, C_, C_);
}